// Round 9
// baseline (934.776 us; speedup 1.0000x reference)
//
#include <hip/hip_runtime.h>
#include <math.h>

#define CC 20
#define BB 256
#define HH 10
#define SS 64
#define AA 16
#define HD 128
#define RH 64
#define CBR (CC*BB)      // 5120 rows
#define NSNN 15
#define RT 2             // rows per block (row tiling)

// Replicate npy_logaddexpf(u, 0.f): float32 chain, expf/log1pf at
// correctly-rounded level via f64 internals. (Verified bit-exact rounds 4-8.)
__device__ __forceinline__ float softplus_np(float u) {
    if (u > 0.0f) {
        float ef = (float)exp((double)(-u));
        float l1 = (float)log1p((double)ef);
        return __fadd_rn(u, l1);
    } else if (u < 0.0f) {
        float ef = (float)exp((double)u);
        return (float)log1p((double)ef);
    } else {
        return 0.69314718055994530942f;
    }
}

// One block = RT(=2) rollout rows, ONE horizon step h. 128 threads, thread j
// = hidden unit j for BOTH rows: every weight load is amortized over 2 rows
// (round 8 showed ~46% of L2 BW + 4x VALU-overhead from per-row weight
// re-loads). Staged activations live in LDS as [i][RT] so both rows read as
// one float2.
//
// All per-row dot products remain single sequential-k fmaf chains and all
// elementwise ops separately rounded — bit-exact vs np-f32 (rounds 4-8).
// k-loops pinned rolled (#pragma unroll 1) to prevent the round-5/7 VGPR
// blowup; t-loops fully unrolled so cur2[][] stays in registers.
__global__ __launch_bounds__(128) void world_kernel(
    int h,
    const float* __restrict__ current_state,   // [B,S]
    const float* __restrict__ actions,         // [C,B,H,A]
    const float* __restrict__ noise,           // [C,B,H,S]
    const float* __restrict__ Wse, const float* __restrict__ bse,
    const float* __restrict__ Wae, const float* __restrict__ bae,
    const float* __restrict__ W1,  const float* __restrict__ b1,
    const float* __restrict__ W2,  const float* __restrict__ b2,
    const float* __restrict__ Wdec, const float* __restrict__ bdec,
    const float* __restrict__ Wunc, const float* __restrict__ bunc,
    float* __restrict__ states)                // [H, CB, S]
{
    const int cb0 = blockIdx.x * RT;
    const int j   = threadIdx.x;

    __shared__ float    s_state[SS][RT];
    __shared__ float    s_sae[2*HD][RT];
    __shared__ unsigned s_mask[HD][RT];
    __shared__ float    s_mem2[HD][RT];
    __shared__ float    s_mu[2*SS][RT];   // [0..63]=mean, [64..127]=u

    if (j < SS) {
        #pragma unroll
        for (int r = 0; r < RT; r++) {
            int cb = cb0 + r;
            s_state[j][r] = (h == 0) ? current_state[(size_t)(cb % BB)*SS + j]
                                     : states[((size_t)(h-1)*CBR + cb)*SS + j];
        }
    }
    __syncthreads();

    // ---- se = relu(state @ Wse + bse): per-row sequential-k single chain
    float a0 = 0.0f, a1 = 0.0f;
    for (int i = 0; i < SS; i++) {
        float w = Wse[i*HD + j];
        float2 st = *(const float2*)&s_state[i][0];
        a0 = fmaf(st.x, w, a0);
        a1 = fmaf(st.y, w, a1);
    }
    float se0 = fmaxf(__fadd_rn(a0, bse[j]), 0.0f);
    float se1 = fmaxf(__fadd_rn(a1, bse[j]), 0.0f);

    // ---- ae = relu(act @ Wae + bae)
    const float* act0 = actions + ((size_t)(cb0+0)*HH + h)*AA;
    const float* act1 = actions + ((size_t)(cb0+1)*HH + h)*AA;
    a0 = 0.0f; a1 = 0.0f;
    for (int i = 0; i < AA; i++) {
        float w = Wae[i*HD + j];
        a0 = fmaf(act0[i], w, a0);
        a1 = fmaf(act1[i], w, a1);
    }
    float ae0 = fmaxf(__fadd_rn(a0, bae[j]), 0.0f);
    float ae1 = fmaxf(__fadd_rn(a1, bae[j]), 0.0f);

    s_sae[j][0]      = se0;  s_sae[j][1]      = se1;
    s_sae[HD + j][0] = ae0;  s_sae[HD + j][1] = ae1;
    __syncthreads();

    // ---- cur = concat(se, ae) @ W1 + b1 (constant across SNN steps)
    a0 = 0.0f; a1 = 0.0f;
    for (int i = 0; i < 2*HD; i++) {
        float w = W1[i*HD + j];
        float2 sv = *(const float2*)&s_sae[i][0];
        a0 = fmaf(sv.x, w, a0);
        a1 = fmaf(sv.y, w, a1);
    }
    const float cur0 = __fadd_rn(a0, b1[j]);
    const float cur1 = __fadd_rn(a1, b1[j]);

    // ---- mem1 recurrence -> 15-bit spike mask per row (exact op order)
    unsigned mask0 = 0u, mask1 = 0u;
    {
        float m1a = 0.0f, m1b = 0.0f;
        #pragma unroll
        for (int t = 0; t < NSNN; t++) {
            float spa = (__fsub_rn(m1a, 1.0f) > 0.0f) ? 1.0f : 0.0f;
            m1a = __fsub_rn(__fadd_rn(__fmul_rn(0.9f, m1a), cur0), spa);
            if (__fsub_rn(m1a, 1.0f) > 0.0f) mask0 |= (1u << t);
            float spb = (__fsub_rn(m1b, 1.0f) > 0.0f) ? 1.0f : 0.0f;
            m1b = __fsub_rn(__fadd_rn(__fmul_rn(0.9f, m1b), cur1), spb);
            if (__fsub_rn(m1b, 1.0f) > 0.0f) mask1 |= (1u << t);
        }
    }
    s_mask[j][0] = mask0;
    s_mask[j][1] = mask1;
    __syncthreads();

    // ---- cache masks in 4 VGPRs/lane (lane = j & 63; both waves identical)
    const int lane = j & 63;
    unsigned mlo0 = s_mask[lane][0],      mlo1 = s_mask[lane][1];
    unsigned mhi0 = s_mask[64 + lane][0], mhi1 = s_mask[64 + lane][1];

    // ---- cur2[t] = spk[t] @ W2: one k-ascending pass, both rows share the
    // weight load. fmaf(sv in {0,1}, w, acc) is an exact identity at sv=0,
    // so each chain is bit-identical to the reference.
    float c20[NSNN], c21[NSNN];
    #pragma unroll
    for (int t = 0; t < NSNN; t++) { c20[t] = 0.0f; c21[t] = 0.0f; }

    const float* W2j = W2 + j;
    #pragma unroll 1
    for (int k = 0; k < 64; k++) {
        float w = W2j[(size_t)k * HD];
        unsigned m0 = (unsigned)__builtin_amdgcn_readlane((int)mlo0, k);
        unsigned m1 = (unsigned)__builtin_amdgcn_readlane((int)mlo1, k);
        if (m0) {
            #pragma unroll
            for (int t = 0; t < NSNN; t++) {
                float sv = __uint_as_float(((m0 >> t) & 1u) * 0x3f800000u);
                c20[t] = fmaf(sv, w, c20[t]);
            }
        }
        if (m1) {
            #pragma unroll
            for (int t = 0; t < NSNN; t++) {
                float sv = __uint_as_float(((m1 >> t) & 1u) * 0x3f800000u);
                c21[t] = fmaf(sv, w, c21[t]);
            }
        }
    }
    #pragma unroll 1
    for (int k = 0; k < 64; k++) {
        float w = W2j[(size_t)(64 + k) * HD];
        unsigned m0 = (unsigned)__builtin_amdgcn_readlane((int)mhi0, k);
        unsigned m1 = (unsigned)__builtin_amdgcn_readlane((int)mhi1, k);
        if (m0) {
            #pragma unroll
            for (int t = 0; t < NSNN; t++) {
                float sv = __uint_as_float(((m0 >> t) & 1u) * 0x3f800000u);
                c20[t] = fmaf(sv, w, c20[t]);
            }
        }
        if (m1) {
            #pragma unroll
            for (int t = 0; t < NSNN; t++) {
                float sv = __uint_as_float(((m1 >> t) & 1u) * 0x3f800000u);
                c21[t] = fmaf(sv, w, c21[t]);
            }
        }
    }

    // ---- mem2 recurrence per row (exact op order)
    const float b2j = b2[j];
    {
        float m2a = 0.0f, m2b = 0.0f;
        #pragma unroll
        for (int t = 0; t < NSNN; t++) {
            float ca = __fadd_rn(c20[t], b2j);
            float spa = (__fsub_rn(m2a, 1.0f) > 0.0f) ? 1.0f : 0.0f;
            m2a = __fsub_rn(__fadd_rn(__fmul_rn(0.9f, m2a), ca), spa);
            float cb_ = __fadd_rn(c21[t], b2j);
            float spb = (__fsub_rn(m2b, 1.0f) > 0.0f) ? 1.0f : 0.0f;
            m2b = __fsub_rn(__fadd_rn(__fmul_rn(0.9f, m2b), cb_), spb);
        }
        s_mem2[j][0] = m2a;
        s_mem2[j][1] = m2b;
    }
    __syncthreads();

    // ---- decode, wave-split: threads 0..63 mean, 64..127 unc; both rows
    {
        const float* W    = (j < SS) ? Wdec : Wunc;
        const float* bias = (j < SS) ? bdec : bunc;
        int o = j & (SS - 1);
        float c0 = 0.0f, c1 = 0.0f;
        for (int n = 0; n < HD; n++) {
            float w = W[n*SS + o];
            float2 m2v = *(const float2*)&s_mem2[n][0];
            c0 = fmaf(m2v.x, w, c0);
            c1 = fmaf(m2v.y, w, c1);
        }
        s_mu[j][0] = __fadd_rn(c0, bias[o]);
        s_mu[j][1] = __fadd_rn(c1, bias[o]);
    }
    __syncthreads();

    // ---- sample next state (both rows)
    if (j < SS) {
        #pragma unroll
        for (int r = 0; r < RT; r++) {
            int cb = cb0 + r;
            float mean = s_mu[j][r];
            float u    = s_mu[SS + j][r];
            float var  = softplus_np(u);
            float sv   = sqrtf(__fadd_rn(var, 1e-8f));
            float nz   = noise[((size_t)cb*HH + h)*SS + j];
            states[((size_t)h*CBR + cb)*SS + j] = __fadd_rn(mean, __fmul_rn(nz, sv));
        }
    }
}

// One block = one row (cb), 64 threads; loops over H, f32 sequential sum.
// (Round-4 verified bit-exact, unchanged.)
__global__ __launch_bounds__(64) void reward_kernel(
    const float* __restrict__ states,    // [H, CB, S]
    const float* __restrict__ actions,   // [C,B,H,A]
    const float* __restrict__ Wr1, const float* __restrict__ br1,
    const float* __restrict__ Wr2, const float* __restrict__ br2,
    const float* __restrict__ Wr3, const float* __restrict__ br3,
    float* __restrict__ cum)             // [CB]
{
    const int cb = blockIdx.x;
    const int j  = threadIdx.x;
    __shared__ float s_x[SS + AA];
    __shared__ float s_h[RH];
    __shared__ float s_h2[RH];

    float total = 0.0f;
    for (int h = 0; h < HH; h++) {
        __syncthreads();
        s_x[j] = states[((size_t)h*CBR + cb)*SS + j];
        if (j < AA) s_x[SS + j] = actions[((size_t)cb*HH + h)*AA + j];
        __syncthreads();

        float a = 0.0f;
        for (int i = 0; i < SS + AA; i++)
            a = fmaf(s_x[i], Wr1[i*RH + j], a);
        s_h[j] = fmaxf(__fadd_rn(a, br1[j]), 0.0f);
        __syncthreads();

        float g = 0.0f;
        for (int i = 0; i < RH; i++)
            g = fmaf(s_h[i], Wr2[i*RH + j], g);
        s_h2[j] = fmaxf(__fadd_rn(g, br2[j]), 0.0f);
        __syncthreads();

        if (j == 0) {
            float r = 0.0f;
            for (int k = 0; k < RH; k++)
                r = fmaf(s_h2[k], Wr3[k], r);
            r = __fadd_rn(r, br3[0]);
            total = __fadd_rn(total, r);          // sequential sum over h
        }
    }
    if (j == 0) cum[cb] = total;
}

// One block per batch element b: f32 argmax over C (strict > = first max),
// gather best action. (Bit-exact, unchanged.)
__global__ __launch_bounds__(64) void select_kernel(
    const float* __restrict__ cum,      // [CB], cb = c*B + b
    const float* __restrict__ actions,  // [C,B,H,A]
    float* __restrict__ out)            // [B*H*A] actions then [B] values
{
    const int b = blockIdx.x;
    const int j = threadIdx.x;
    __shared__ int s_c;

    if (j == 0) {
        float best = cum[b];            // c = 0
        int bc = 0;
        for (int c = 1; c < CC; c++) {
            float v = cum[(size_t)c*BB + b];
            if (v > best) { best = v; bc = c; }
        }
        s_c = bc;
        out[(size_t)BB*HH*AA + b] = best;
    }
    __syncthreads();
    const int bc = s_c;
    const float* src = actions + ((size_t)bc*BB + b)*HH*AA;
    for (int i = j; i < HH*AA; i += 64) out[(size_t)b*HH*AA + i] = src[i];
}

extern "C" void kernel_launch(void* const* d_in, const int* in_sizes, int n_in,
                              void* d_out, int out_size, void* d_ws, size_t ws_size,
                              hipStream_t stream)
{
    const float* current_state = (const float*)d_in[0];
    const float* actions = (const float*)d_in[1];
    const float* noise   = (const float*)d_in[2];
    const float* Wse = (const float*)d_in[3];
    const float* bse = (const float*)d_in[4];
    const float* Wae = (const float*)d_in[5];
    const float* bae = (const float*)d_in[6];
    const float* W1  = (const float*)d_in[7];
    const float* b1  = (const float*)d_in[8];
    const float* W2  = (const float*)d_in[9];
    const float* b2  = (const float*)d_in[10];
    const float* Wdec = (const float*)d_in[11];
    const float* bdec = (const float*)d_in[12];
    const float* Wunc = (const float*)d_in[13];
    const float* bunc = (const float*)d_in[14];
    const float* Wr1 = (const float*)d_in[15];
    const float* br1 = (const float*)d_in[16];
    const float* Wr2 = (const float*)d_in[17];
    const float* br2 = (const float*)d_in[18];
    const float* Wr3 = (const float*)d_in[19];
    const float* br3 = (const float*)d_in[20];

    float* states = (float*)d_ws;                       // 10*5120*64 f32 = 13.1 MB
    float* cum    = states + (size_t)HH*CBR*SS;         // 5120 f32

    for (int h = 0; h < HH; h++) {
        world_kernel<<<CBR/RT, HD, 0, stream>>>(h, current_state, actions, noise,
            Wse, bse, Wae, bae, W1, b1, W2, b2, Wdec, bdec, Wunc, bunc, states);
    }
    reward_kernel<<<CBR, RH, 0, stream>>>(states, actions, Wr1, br1, Wr2, br2, Wr3, br3, cum);
    select_kernel<<<BB, 64, 0, stream>>>(cum, actions, (float*)d_out);
}

// Round 10
// 811.052 us; speedup vs baseline: 1.1525x; 1.1525x over previous
//
#include <hip/hip_runtime.h>
#include <math.h>

#define CC 20
#define BB 256
#define HH 10
#define SS 64
#define AA 16
#define HD 128
#define RH 64
#define CBR (CC*BB)      // 5120 rows
#define NSNN 15
#define RT 2             // rows per block, one wave-pair per row

// Replicate npy_logaddexpf(u, 0.f): float32 chain, expf/log1pf at
// correctly-rounded level via f64 internals. (Verified bit-exact rounds 4-9.)
__device__ __forceinline__ float softplus_np(float u) {
    if (u > 0.0f) {
        float ef = (float)exp((double)(-u));
        float l1 = (float)log1p((double)ef);
        return __fadd_rn(u, l1);
    } else if (u < 0.0f) {
        float ef = (float)exp((double)u);
        return (float)log1p((double)ef);
    } else {
        return 0.69314718055994530942f;
    }
}

// One block = RT(=2) rollout rows, ONE horizon step h. 256 threads: row =
// tid>>7 (its own wave-pair), j = tid&127 = hidden unit. Per-row code is
// byte-identical to round 8's proven 36-VGPR body — rows share weights via
// L1 (both wave-pairs march the same addresses in barrier-locked phase), NOT
// via per-thread dual chains (round 9 showed that trades away occupancy).
//
// All dots are single sequential-k fmaf chains; elementwise ops separately
// rounded (__f*_rn) — bit-exact vs np-f32 (verified rounds 4-9). k-loops
// pinned rolled (#pragma unroll 1) to block the round-5/7 VGPR blowup;
// t-loops fully unrolled so cur2[] stays in registers.
__global__ __launch_bounds__(256) void world_kernel(
    int h,
    const float* __restrict__ current_state,   // [B,S]
    const float* __restrict__ actions,         // [C,B,H,A]
    const float* __restrict__ noise,           // [C,B,H,S]
    const float* __restrict__ Wse, const float* __restrict__ bse,
    const float* __restrict__ Wae, const float* __restrict__ bae,
    const float* __restrict__ W1,  const float* __restrict__ b1,
    const float* __restrict__ W2,  const float* __restrict__ b2,
    const float* __restrict__ Wdec, const float* __restrict__ bdec,
    const float* __restrict__ Wunc, const float* __restrict__ bunc,
    float* __restrict__ states)                // [H, CB, S]
{
    const int r  = threadIdx.x >> 7;           // row within block
    const int j  = threadIdx.x & 127;          // hidden unit
    const int cb = blockIdx.x * RT + r;

    __shared__ float    s_state[RT][SS];
    __shared__ float    s_sae[RT][2*HD];
    __shared__ unsigned s_mask[RT][HD];
    __shared__ float    s_mem2[RT][HD];
    __shared__ float    s_mu[RT][2*SS];   // [0..63]=mean, [64..127]=u

    if (j < SS) {
        s_state[r][j] = (h == 0) ? current_state[(size_t)(cb % BB)*SS + j]
                                 : states[((size_t)(h-1)*CBR + cb)*SS + j];
    }
    __syncthreads();

    // ---- se = relu(state @ Wse + bse): sequential-k single chain
    float acc = 0.0f;
    for (int i = 0; i < SS; i++)
        acc = fmaf(s_state[r][i], Wse[i*HD + j], acc);
    float se = fmaxf(__fadd_rn(acc, bse[j]), 0.0f);

    // ---- ae = relu(act @ Wae + bae)
    const float* act = actions + ((size_t)cb*HH + h)*AA;
    acc = 0.0f;
    for (int i = 0; i < AA; i++)
        acc = fmaf(act[i], Wae[i*HD + j], acc);
    float ae = fmaxf(__fadd_rn(acc, bae[j]), 0.0f);

    s_sae[r][j]      = se;
    s_sae[r][HD + j] = ae;
    __syncthreads();

    // ---- cur = concat(se, ae) @ W1 + b1 (constant across SNN steps)
    acc = 0.0f;
    for (int i = 0; i < 2*HD; i++)
        acc = fmaf(s_sae[r][i], W1[i*HD + j], acc);
    const float cur = __fadd_rn(acc, b1[j]);

    // ---- mem1 recurrence -> 15-bit spike mask (exact op order)
    unsigned mask = 0u;
    float m1 = 0.0f;
    #pragma unroll
    for (int t = 0; t < NSNN; t++) {
        float sp1old = (__fsub_rn(m1, 1.0f) > 0.0f) ? 1.0f : 0.0f;
        m1 = __fsub_rn(__fadd_rn(__fmul_rn(0.9f, m1), cur), sp1old);
        if (__fsub_rn(m1, 1.0f) > 0.0f) mask |= (1u << t);
    }
    s_mask[r][j] = mask;
    __syncthreads();

    // ---- cache this row's 128 masks in 2 VGPRs per lane (lane = j & 63;
    // both waves of the pair hold identical copies)
    const int lane = j & 63;
    unsigned mlo = s_mask[r][lane];
    unsigned mhi = s_mask[r][64 + lane];

    // ---- cur2[t] = spk[t] @ W2, one k-ascending pass, all 15 t at once.
    // fmaf(sv in {0,1}, w, acc) with sv=0 is an exact identity (acc stays
    // +0 under skips), so each cur2[t] equals the reference's sequential
    // chain bit-for-bit. Mask via readlane -> SGPR (SALU control path);
    // m==0 units skipped by wave-uniform scalar branch.
    float cur2[NSNN];
    #pragma unroll
    for (int t = 0; t < NSNN; t++) cur2[t] = 0.0f;

    const float* W2j = W2 + j;
    #pragma unroll 1
    for (int k = 0; k < 64; k++) {
        float w = W2j[(size_t)k * HD];
        unsigned m = (unsigned)__builtin_amdgcn_readlane((int)mlo, k);
        if (m == 0u) continue;
        #pragma unroll
        for (int t = 0; t < NSNN; t++) {
            float sv = __uint_as_float(((m >> t) & 1u) * 0x3f800000u);
            cur2[t] = fmaf(sv, w, cur2[t]);
        }
    }
    #pragma unroll 1
    for (int k = 0; k < 64; k++) {
        float w = W2j[(size_t)(64 + k) * HD];
        unsigned m = (unsigned)__builtin_amdgcn_readlane((int)mhi, k);
        if (m == 0u) continue;
        #pragma unroll
        for (int t = 0; t < NSNN; t++) {
            float sv = __uint_as_float(((m >> t) & 1u) * 0x3f800000u);
            cur2[t] = fmaf(sv, w, cur2[t]);
        }
    }

    // ---- mem2 recurrence (exact op order)
    const float b2j = b2[j];
    float m2 = 0.0f;
    #pragma unroll
    for (int t = 0; t < NSNN; t++) {
        float c2 = __fadd_rn(cur2[t], b2j);
        float sp2old = (__fsub_rn(m2, 1.0f) > 0.0f) ? 1.0f : 0.0f;
        m2 = __fsub_rn(__fadd_rn(__fmul_rn(0.9f, m2), c2), sp2old);
    }
    s_mem2[r][j] = m2;
    __syncthreads();

    // ---- decode, wave-split: threads 0..63 mean, 64..127 unc
    {
        const float* W    = (j < SS) ? Wdec : Wunc;
        const float* bias = (j < SS) ? bdec : bunc;
        int o = j & (SS - 1);
        float c = 0.0f;
        for (int n = 0; n < HD; n++)
            c = fmaf(s_mem2[r][n], W[n*SS + o], c);
        s_mu[r][j] = __fadd_rn(c, bias[o]);
    }
    __syncthreads();

    // ---- sample next state
    if (j < SS) {
        float mean = s_mu[r][j];
        float u    = s_mu[r][SS + j];
        float var  = softplus_np(u);
        float sv   = sqrtf(__fadd_rn(var, 1e-8f));
        float nz   = noise[((size_t)cb*HH + h)*SS + j];
        states[((size_t)h*CBR + cb)*SS + j] = __fadd_rn(mean, __fmul_rn(nz, sv));
    }
}

// One block = one row (cb), 64 threads; loops over H. The only serial part
// (the 64-FMA h2@Wr3 chain) now runs for all 10 h IN PARALLEL (threads 0..9,
// each its own sequential chain), then thread 0 folds total in ascending-h
// order — op-for-op identical to the reference, so still bit-exact.
__global__ __launch_bounds__(64) void reward_kernel(
    const float* __restrict__ states,    // [H, CB, S]
    const float* __restrict__ actions,   // [C,B,H,A]
    const float* __restrict__ Wr1, const float* __restrict__ br1,
    const float* __restrict__ Wr2, const float* __restrict__ br2,
    const float* __restrict__ Wr3, const float* __restrict__ br3,
    float* __restrict__ cum)             // [CB]
{
    const int cb = blockIdx.x;
    const int j  = threadIdx.x;
    __shared__ float s_x[SS + AA];
    __shared__ float s_h[RH];
    __shared__ float s_h2a[HH][RH];
    __shared__ float s_r[HH];

    for (int h = 0; h < HH; h++) {
        __syncthreads();
        s_x[j] = states[((size_t)h*CBR + cb)*SS + j];
        if (j < AA) s_x[SS + j] = actions[((size_t)cb*HH + h)*AA + j];
        __syncthreads();

        float a = 0.0f;
        for (int i = 0; i < SS + AA; i++)
            a = fmaf(s_x[i], Wr1[i*RH + j], a);
        s_h[j] = fmaxf(__fadd_rn(a, br1[j]), 0.0f);
        __syncthreads();

        float g = 0.0f;
        for (int i = 0; i < RH; i++)
            g = fmaf(s_h[i], Wr2[i*RH + j], g);
        s_h2a[h][j] = fmaxf(__fadd_rn(g, br2[j]), 0.0f);
    }
    __syncthreads();

    if (j < HH) {
        float rr = 0.0f;                      // sequential-k chain, own h
        for (int k = 0; k < RH; k++)
            rr = fmaf(s_h2a[j][k], Wr3[k], rr);
        s_r[j] = __fadd_rn(rr, br3[0]);
    }
    __syncthreads();

    if (j == 0) {
        float total = 0.0f;
        for (int h = 0; h < HH; h++)
            total = __fadd_rn(total, s_r[h]); // sequential sum over h
        cum[cb] = total;
    }
}

// One block per batch element b: f32 argmax over C (strict > = first max),
// gather best action. (Bit-exact, unchanged.)
__global__ __launch_bounds__(64) void select_kernel(
    const float* __restrict__ cum,      // [CB], cb = c*B + b
    const float* __restrict__ actions,  // [C,B,H,A]
    float* __restrict__ out)            // [B*H*A] actions then [B] values
{
    const int b = blockIdx.x;
    const int j = threadIdx.x;
    __shared__ int s_c;

    if (j == 0) {
        float best = cum[b];            // c = 0
        int bc = 0;
        for (int c = 1; c < CC; c++) {
            float v = cum[(size_t)c*BB + b];
            if (v > best) { best = v; bc = c; }
        }
        s_c = bc;
        out[(size_t)BB*HH*AA + b] = best;
    }
    __syncthreads();
    const int bc = s_c;
    const float* src = actions + ((size_t)bc*BB + b)*HH*AA;
    for (int i = j; i < HH*AA; i += 64) out[(size_t)b*HH*AA + i] = src[i];
}

extern "C" void kernel_launch(void* const* d_in, const int* in_sizes, int n_in,
                              void* d_out, int out_size, void* d_ws, size_t ws_size,
                              hipStream_t stream)
{
    const float* current_state = (const float*)d_in[0];
    const float* actions = (const float*)d_in[1];
    const float* noise   = (const float*)d_in[2];
    const float* Wse = (const float*)d_in[3];
    const float* bse = (const float*)d_in[4];
    const float* Wae = (const float*)d_in[5];
    const float* bae = (const float*)d_in[6];
    const float* W1  = (const float*)d_in[7];
    const float* b1  = (const float*)d_in[8];
    const float* W2  = (const float*)d_in[9];
    const float* b2  = (const float*)d_in[10];
    const float* Wdec = (const float*)d_in[11];
    const float* bdec = (const float*)d_in[12];
    const float* Wunc = (const float*)d_in[13];
    const float* bunc = (const float*)d_in[14];
    const float* Wr1 = (const float*)d_in[15];
    const float* br1 = (const float*)d_in[16];
    const float* Wr2 = (const float*)d_in[17];
    const float* br2 = (const float*)d_in[18];
    const float* Wr3 = (const float*)d_in[19];
    const float* br3 = (const float*)d_in[20];

    float* states = (float*)d_ws;                       // 10*5120*64 f32 = 13.1 MB
    float* cum    = states + (size_t)HH*CBR*SS;         // 5120 f32

    for (int h = 0; h < HH; h++) {
        world_kernel<<<CBR/RT, RT*HD, 0, stream>>>(h, current_state, actions, noise,
            Wse, bse, Wae, bae, W1, b1, W2, b2, Wdec, bdec, Wunc, bunc, states);
    }
    reward_kernel<<<CBR, RH, 0, stream>>>(states, actions, Wr1, br1, Wr2, br2, Wr3, br3, cum);
    select_kernel<<<BB, 64, 0, stream>>>(cum, actions, (float*)d_out);
}